// Round 10
// baseline (100.985 us; speedup 1.0000x reference)
//
#include <hip/hip_runtime.h>

// ---------------------------------------------------------------------------
// Causal SDPA, B=8, S=2048, D=64, fp32 in/out.
//   prep_f16: K -> Kh (f16 row-major, pre-scaled by log2e/sqrt(D));
//             V -> Vq (f16 packed [B][S/16][64][16], coalesced PV frags);
//             M -> Mf (float bias: 0 attend, -1e5 masked).
//   attn_f16_v8: v6's K-loop (best so far) restructured for 2x TLP:
//     256-thr blocks (4 waves), ONE 16-row q-frag per wave, 4-way split-K.
//     sO down to 17.4 KB, launch_bounds(256,4) => <=128 VGPR, 4 blocks/CU
//     resident = 4 waves/SIMD (v6/v7 ran 2 — every un-modeled stall was
//     exposed raw; TLP is the one axis never raised).
//     Flat grid 1024: tile = 127-(idx>>3), batch = idx&7 => biggest tiles of
//     ALL batches dispatch first (machine-wide LPT).
//     Loop per tile: V+mask issued at top, S^T = K·Q^T on 1-deep prefetched
//     K frags (P stays in registers, K=16 PV MFMAs), mask as exp2-bias,
//     causal cndmask only on the diagonal tile.
// Fallback (ws too small): R2-style kernel on fp32 inputs.
// ---------------------------------------------------------------------------

typedef _Float16 f16x8 __attribute__((ext_vector_type(8)));
typedef _Float16 f16x4 __attribute__((ext_vector_type(4)));
typedef float    f32x4 __attribute__((ext_vector_type(4)));

#define MFMA_K32(A, B, C) __builtin_amdgcn_mfma_f32_16x16x32_f16(A, B, C, 0, 0, 0)
#define MFMA_K16(A, B, C) __builtin_amdgcn_mfma_f32_16x16x16f16(A, B, C, 0, 0, 0)

__device__ inline unsigned pack2h(float a, float b) {
    union { _Float16 h[2]; unsigned u; } t;
    t.h[0] = (_Float16)a; t.h[1] = (_Float16)b;
    return t.u;
}

constexpr float CSCALE = 0.18033688011112042f;   // log2(e)/sqrt(64)

// -- prep: Kh = f16(K*CSCALE); Vq packed [B,S/16,64,16]; Mf float bias ------
__global__ __launch_bounds__(256, 4)
void prep_f16(const float* __restrict__ K, const float* __restrict__ V,
              const int* __restrict__ M, _Float16* __restrict__ Kh,
              _Float16* __restrict__ Vq, float* __restrict__ Mf) {
    __shared__ _Float16 sT[64 * 80];          // [d][local_s]
    const int b   = blockIdx.x >> 5;
    const int s0  = (blockIdx.x & 31) * 64;
    const int t   = threadIdx.x;
    const int row = t >> 2;                   // local s 0..63
    const int grp = (t & 3) * 16;             // d group
    const size_t base = ((size_t)b * 2048 + s0 + row) * 64 + grp;
    {   // K: scale + convert, row-major
        union { _Float16 h[16]; f16x8 v[2]; } o;
        const float* p = K + base;
#pragma unroll
        for (int i = 0; i < 16; i += 4) {
            float4 x = *(const float4*)(p + i);
            o.h[i]   = (_Float16)(x.x * CSCALE); o.h[i+1] = (_Float16)(x.y * CSCALE);
            o.h[i+2] = (_Float16)(x.z * CSCALE); o.h[i+3] = (_Float16)(x.w * CSCALE);
        }
        *(f16x8*)(Kh + base) = o.v[0];
        *(f16x8*)(Kh + base + 8) = o.v[1];
    }
    {   // V: convert into LDS transposed sT[d][local_s]
        const float* p = V + base;
#pragma unroll
        for (int i = 0; i < 16; i += 4) {
            float4 x = *(const float4*)(p + i);
            sT[(grp + i    ) * 80 + row] = (_Float16)x.x;
            sT[(grp + i + 1) * 80 + row] = (_Float16)x.y;
            sT[(grp + i + 2) * 80 + row] = (_Float16)x.z;
            sT[(grp + i + 3) * 80 + row] = (_Float16)x.w;
        }
    }
    if (t < 64) {   // mask -> float bias (0 attend, -1e5 masked)
        const size_t s = (size_t)b * 2048 + s0 + t;
        Mf[s] = M[s] ? 0.f : -1.0e5f;
    }
    __syncthreads();
    {   // Vq[b][s>>4][d][s&15]
        const int d = t & 63, g = t >> 6;
        const size_t o = (((size_t)b * 128 + (s0 >> 4) + g) * 64 + d) * 16;
        *(f16x8*)(Vq + o)     = *(const f16x8*)&sT[d * 80 + g * 16];
        *(f16x8*)(Vq + o + 8) = *(const f16x8*)&sT[d * 80 + g * 16 + 8];
    }
}

// -------- v8: 256-thr blocks, 4-way split-K, 4 waves/SIMD ------------------
constexpr int SOSTR = 68;   // padded fp32 row stride for sO

__global__ __launch_bounds__(256, 4)
void attn_f16_v8(const float* __restrict__ Q, const _Float16* __restrict__ Kh,
                 const _Float16* __restrict__ Vq, const float* __restrict__ Mf,
                 float* __restrict__ O) {
    constexpr int S = 2048, D = 64;

    __shared__ float sO[4][16 * SOSTR];   // 17.4 KB partial O
    __shared__ float sL[4][16];           // partial denominators

    const int tid  = threadIdx.x;
    const int w    = tid >> 6;            // wave 0..3
    const int lane = tid & 63;
    const int l15  = lane & 15;
    const int quad = lane >> 4;

    const int idx   = (int)blockIdx.x;
    const int tile  = 127 - (idx >> 3);   // big tiles dispatch first, all batches
    const int batch = idx & 7;
    const int n_kt  = tile / 2 + 1;       // 32-key tiles (causal)
    const int qg0   = tile * 16;
    const size_t bq = (size_t)batch * S;
    const _Float16* Kb = Kh + bq * D;
    const _Float16* Vb = Vq + bq * D;
    const float*    Mb = Mf + bq;

    // Q fragment: Q[qg0+l15][quad*8 + dc*32 + j]
    f16x8 qf[2];
    {
        const float* qp = Q + (bq + qg0 + l15) * D + quad * 8;
#pragma unroll
        for (int dc = 0; dc < 2; ++dc) {
            float4 x0 = *(const float4*)(qp + dc * 32);
            float4 x1 = *(const float4*)(qp + dc * 32 + 4);
            union { unsigned u[4]; f16x8 v; } t;
            t.u[0] = pack2h(x0.x, x0.y); t.u[1] = pack2h(x0.z, x0.w);
            t.u[2] = pack2h(x1.x, x1.y); t.u[3] = pack2h(x1.z, x1.w);
            qf[dc] = t.v;
        }
    }

    f32x4 acc[4];
    float lacc = 0.f;
#pragma unroll
    for (int c = 0; c < 4; ++c) { acc[c][0] = acc[c][1] = acc[c][2] = acc[c][3] = 0.f; }

    // ---- prime K prefetch for tile t = w ---------------------------------
    f16x8 kn[2][2];
    if (w < n_kt) {
        const int kb = w * 32;
#pragma unroll
        for (int kg = 0; kg < 2; ++kg)
#pragma unroll
            for (int dc = 0; dc < 2; ++dc)
                kn[kg][dc] = *(const f16x8*)(Kb + (size_t)(kb + kg * 16 + l15) * D + dc * 32 + quad * 8);
    }

    for (int t = w; t < n_kt; t += 4) {
        const int kb = t * 32;

        // ---- issue V + mask for THIS tile (used after the QK^T MFMAs) ----
        f16x4 vf[2][4];
#pragma unroll
        for (int kg = 0; kg < 2; ++kg)
#pragma unroll
            for (int c = 0; c < 4; ++c)
                vf[kg][c] = *(const f16x4*)(Vb + ((size_t)((kb >> 4) + kg) * 64 + c * 16 + l15) * 16 + quad * 4);
        float4 mbias0 = *(const float4*)(Mb + kb + quad * 4);
        float4 mbias1 = *(const float4*)(Mb + kb + 16 + quad * 4);

        // ---- S^T = K Q^T on prefetched K frags ---------------------------
        f32x4 scT0, scT1;
        {
            f32x4 z; z[0] = z[1] = z[2] = z[3] = 0.f;
            f32x4 y0 = MFMA_K32(kn[0][0], qf[0], z);
            scT0 = MFMA_K32(kn[0][1], qf[1], y0);
            f32x4 y1 = MFMA_K32(kn[1][0], qf[0], z);
            scT1 = MFMA_K32(kn[1][1], qf[1], y1);
        }

        // ---- issue next tile's K loads -----------------------------------
        if (t + 4 < n_kt) {
            const int kb2 = kb + 128;
#pragma unroll
            for (int kg = 0; kg < 2; ++kg)
#pragma unroll
                for (int dc = 0; dc < 2; ++dc)
                    kn[kg][dc] = *(const f16x8*)(Kb + (size_t)(kb2 + kg * 16 + l15) * D + dc * 32 + quad * 8);
        }

        // ---- masked exp; P lands in K=16 A-operand layout ----------------
        const bool diag = (kb + 32 > qg0);   // only the diagonal tile
        const int qrow = qg0 + l15;
        f16x4 pf0, pf1;
        {
            union { _Float16 h[4]; f16x4 v; } pp;
            const float mb0[4] = {mbias0.x, mbias0.y, mbias0.z, mbias0.w};
#pragma unroll
            for (int r = 0; r < 4; ++r) {
                float e = __builtin_amdgcn_exp2f(scT0[r] + mb0[r]);
                if (diag) {
                    const int key = kb + quad * 4 + r;
                    e = (key <= qrow) ? e : 0.f;
                }
                lacc += e;
                pp.h[r] = (_Float16)e;
            }
            pf0 = pp.v;
            const float mb1[4] = {mbias1.x, mbias1.y, mbias1.z, mbias1.w};
#pragma unroll
            for (int r = 0; r < 4; ++r) {
                float e = __builtin_amdgcn_exp2f(scT1[r] + mb1[r]);
                if (diag) {
                    const int key = kb + 16 + quad * 4 + r;
                    e = (key <= qrow) ? e : 0.f;
                }
                lacc += e;
                pp.h[r] = (_Float16)e;
            }
            pf1 = pp.v;
        }

        // ---- O += P V (all registers) ------------------------------------
        acc[0] = MFMA_K16(pf0, vf[0][0], acc[0]);
        acc[1] = MFMA_K16(pf0, vf[0][1], acc[1]);
        acc[2] = MFMA_K16(pf0, vf[0][2], acc[2]);
        acc[3] = MFMA_K16(pf0, vf[0][3], acc[3]);
        acc[0] = MFMA_K16(pf1, vf[1][0], acc[0]);
        acc[1] = MFMA_K16(pf1, vf[1][1], acc[1]);
        acc[2] = MFMA_K16(pf1, vf[1][2], acc[2]);
        acc[3] = MFMA_K16(pf1, vf[1][3], acc[3]);
    }

    // denom partials: sum over quads (lanes sharing l15)
    lacc += __shfl_xor(lacc, 16, 64);
    lacc += __shfl_xor(lacc, 32, 64);

    // write partials (row q = quad*4+r? no: acc row = quad*4+r -> q col...)
    // acc C-layout: row q... here S^T convention: acc[c][r] is
    // q-row = quad*4 + r?? No: PV output D = P(16q x 16k) x V(16k x 16d):
    // C-layout col = lane&15 = d-within-16? col=lane&15 -> d = c*16 + ???
    // (Same mapping as v4-v7, verified passing: row q = quad*4+r,
    //  col d = c*16 + l15.)
#pragma unroll
    for (int c = 0; c < 4; ++c)
#pragma unroll
        for (int r = 0; r < 4; ++r)
            sO[w][(quad * 4 + r) * SOSTR + c * 16 + l15] = acc[c][r];
    if (lane < 16) sL[w][l15] = lacc;
    __syncthreads();
    {
        const int row = tid >> 4;          // 0..15
        const int col = (tid & 15) * 4;    // 0,4,..,60
        float a0 = 0.f, a1 = 0.f, a2 = 0.f, a3 = 0.f, l = 0.f;
#pragma unroll
        for (int w2 = 0; w2 < 4; ++w2) {
            const float* p = &sO[w2][row * SOSTR + col];
            a0 += p[0]; a1 += p[1]; a2 += p[2]; a3 += p[3];
            l  += sL[w2][row];
        }
        const float inv = 1.f / fmaxf(l, 1e-37f);
        float4 o; o.x = a0 * inv; o.y = a1 * inv; o.z = a2 * inv; o.w = a3 * inv;
        *(float4*)(&O[(bq + qg0 + row) * D + col]) = o;
    }
}

// ---------------- fallback (fp32 inputs, no ws) ----------------------------
constexpr int PSTR = 40;
__global__ __launch_bounds__(512, 4)
void attn_f16_slow(const float* __restrict__ Q, const float* __restrict__ K,
                   const float* __restrict__ V, const int* __restrict__ M,
                   float* __restrict__ O) {
    constexpr int S = 2048, D = 64;
    __shared__ __align__(16) _Float16 sP[8][16 * PSTR];
    __shared__ float sO[8][16 * 64];
    __shared__ float sL[8][16];
    const int tid = threadIdx.x, w = tid >> 6, lane = tid & 63;
    const int l15 = lane & 15, quad = lane >> 4;
    for (int phase = 0; phase < 2; ++phase) {
        const int batch = (int)blockIdx.y ^ phase;
        const int tile  = phase ? 127 - (int)blockIdx.x : (int)blockIdx.x;
        const int n_kt  = tile / 2 + 1;
        const int qg0   = tile * 16;
        const size_t bq = (size_t)batch * S;
        f16x8 qf[2];
        {
            const float* qp = Q + (bq + qg0 + l15) * D + quad * 8;
#pragma unroll
            for (int dc = 0; dc < 2; ++dc) {
                float4 x0 = *(const float4*)(qp + dc * 32);
                float4 x1 = *(const float4*)(qp + dc * 32 + 4);
                union { unsigned u[4]; f16x8 v; } t;
                t.u[0] = pack2h(x0.x, x0.y); t.u[1] = pack2h(x0.z, x0.w);
                t.u[2] = pack2h(x1.x, x1.y); t.u[3] = pack2h(x1.z, x1.w);
                qf[dc] = t.v;
            }
        }
        f32x4 acc[4]; float lacc[4];
#pragma unroll
        for (int c = 0; c < 4; ++c) { acc[c][0] = acc[c][1] = acc[c][2] = acc[c][3] = 0.f; }
#pragma unroll
        for (int r = 0; r < 4; ++r) lacc[r] = 0.f;
        for (int t = w; t < n_kt; t += 8) {
            const int kb = t * 32;
            f16x8 kf[2][2];
            {
                const float* kp = K + (bq + kb + l15) * D + quad * 8;
#pragma unroll
                for (int kg = 0; kg < 2; ++kg)
#pragma unroll
                    for (int dc = 0; dc < 2; ++dc) {
                        float4 x0 = *(const float4*)(kp + kg * 16 * D + dc * 32);
                        float4 x1 = *(const float4*)(kp + kg * 16 * D + dc * 32 + 4);
                        union { unsigned u[4]; f16x8 v; } tt;
                        tt.u[0] = pack2h(x0.x * CSCALE, x0.y * CSCALE);
                        tt.u[1] = pack2h(x0.z * CSCALE, x0.w * CSCALE);
                        tt.u[2] = pack2h(x1.x * CSCALE, x1.y * CSCALE);
                        tt.u[3] = pack2h(x1.z * CSCALE, x1.w * CSCALE);
                        kf[kg][dc] = tt.v;
                    }
            }
            float vr[4][8];
            {
                const float* vp = V + (bq + kb + quad * 8) * D + l15;
#pragma unroll
                for (int c = 0; c < 4; ++c)
#pragma unroll
                    for (int j = 0; j < 8; ++j)
                        vr[c][j] = vp[j * D + c * 16];
            }
            const int m0 = M[bq + kb + l15];
            const int m1 = M[bq + kb + 16 + l15];
            f32x4 sc[2];
#pragma unroll
            for (int kg = 0; kg < 2; ++kg) {
                f32x4 z; z[0] = z[1] = z[2] = z[3] = 0.f;
                z = MFMA_K32(qf[0], kf[kg][0], z);
                sc[kg] = MFMA_K32(qf[1], kf[kg][1], z);
            }
            float p[2][4];
#pragma unroll
            for (int kg = 0; kg < 2; ++kg) {
                const int key = kb + kg * 16 + l15;
                const int mv  = kg ? m1 : m0;
#pragma unroll
                for (int r = 0; r < 4; ++r) {
                    const int qrow = qg0 + quad * 4 + r;
                    float e  = __builtin_amdgcn_exp2f(sc[kg][r]);
                    bool  ok = (key <= qrow) && (mv != 0);
                    float pv = ok ? e : 0.f;
                    p[kg][r] = pv;
                    lacc[r] += pv;
                }
            }
            _Float16* sPw = sP[w];
#pragma unroll
            for (int kg = 0; kg < 2; ++kg)
#pragma unroll
                for (int r = 0; r < 4; ++r)
                    sPw[(quad * 4 + r) * PSTR + kg * 16 + l15] = (_Float16)p[kg][r];
            f16x8 pf = *(const f16x8*)(&sPw[l15 * PSTR + quad * 8]);
#pragma unroll
            for (int c = 0; c < 4; ++c) {
                union { unsigned u[4]; f16x8 v; } tt;
                tt.u[0] = pack2h(vr[c][0], vr[c][1]);
                tt.u[1] = pack2h(vr[c][2], vr[c][3]);
                tt.u[2] = pack2h(vr[c][4], vr[c][5]);
                tt.u[3] = pack2h(vr[c][6], vr[c][7]);
                acc[c] = MFMA_K32(pf, tt.v, acc[c]);
            }
        }
#pragma unroll
        for (int r = 0; r < 4; ++r) {
            float s = lacc[r];
            s += __shfl_xor(s, 1, 64);
            s += __shfl_xor(s, 2, 64);
            s += __shfl_xor(s, 4, 64);
            s += __shfl_xor(s, 8, 64);
            lacc[r] = s;
        }
#pragma unroll
        for (int c = 0; c < 4; ++c)
#pragma unroll
            for (int r = 0; r < 4; ++r)
                sO[w][(quad * 4 + r) * 64 + c * 16 + l15] = acc[c][r];
        if (l15 == 0) {
#pragma unroll
            for (int r = 0; r < 4; ++r) sL[w][quad * 4 + r] = lacc[r];
        }
        __syncthreads();
        {
            const int row = tid >> 5;
            const int col = (tid & 31) * 2;
            float a = 0.f, b = 0.f, l = 0.f;
#pragma unroll
            for (int w2 = 0; w2 < 8; ++w2) {
                a += sO[w2][row * 64 + col];
                b += sO[w2][row * 64 + col + 1];
                l += sL[w2][row];
            }
            const float inv = 1.f / fmaxf(l, 1e-37f);
            float2 o; o.x = a * inv; o.y = b * inv;
            *(float2*)(&O[(bq + qg0 + row) * D + col]) = o;
        }
        __syncthreads();
    }
}

extern "C" void kernel_launch(void* const* d_in, const int* in_sizes, int n_in,
                              void* d_out, int out_size, void* d_ws, size_t ws_size,
                              hipStream_t stream) {
    const float* Q = (const float*)d_in[0];
    const float* K = (const float*)d_in[1];
    const float* V = (const float*)d_in[2];
    const int*   M = (const int*)d_in[3];
    float*       O = (float*)d_out;
    const size_t n_kv = (size_t)8 * 2048 * 64;
    const size_t need = n_kv * 2 * sizeof(_Float16) + (size_t)8 * 2048 * sizeof(float);
    if (ws_size >= need) {
        _Float16* Kh = (_Float16*)d_ws;
        _Float16* Vq = Kh + n_kv;
        float*    Mf = (float*)(Vq + n_kv);
        hipLaunchKernelGGL(prep_f16, dim3(256), dim3(256), 0, stream, K, V, M, Kh, Vq, Mf);
        hipLaunchKernelGGL(attn_f16_v8, dim3(1024), dim3(256), 0, stream, Q, Kh, Vq, Mf, O);
    } else {
        hipLaunchKernelGGL(attn_f16_slow, dim3(64, 8), dim3(512), 0, stream, Q, K, V, M, O);
    }
}

// Round 11
// 87.597 us; speedup vs baseline: 1.1528x; 1.1528x over previous
//
#include <hip/hip_runtime.h>

// ---------------------------------------------------------------------------
// Causal SDPA, B=8, S=2048, D=64, fp32 in/out.
//   prep_f16: K -> Kh (f16 row-major, pre-scaled by log2e/sqrt(D));
//             V -> Vq (f16 packed [B][S/16][64][16], coalesced PV frags);
//             M -> Mf (float bias: 0 attend, -1e5 masked).
//   attn_f16_v9 = v6 (champion: 32-row supertile, 8-wave block, 2-phase
//     balanced pairing, operand-swapped S^T = K·Q^T with register P, K 1-deep
//     prefetch, V+mask at top of iter, mask-as-exp2-bias, diagonal-only
//     causal) + ONE change: XCD-affinity block swizzle.
//       Flat grid 256: batch = idx & 7, st = idx >> 3.
//       XCD = block_id % 8 == batch  =>  each XCD's L2 serves exactly ONE
//       batch's Kh+Vq (1 MB << 4 MB L2). v6's grid(32,8) spread all 8
//       batches (8 MB) across every XCD -> L2 thrash, every fragment read
//       paid L3 (~600cyc) instead of L2 (~200cyc).
//     Pairing phase1: st' = 63-st, batch' = batch^1 (still 1 batch/XCD).
// Fallback (ws too small): R2-style kernel on fp32 inputs.
// ---------------------------------------------------------------------------

typedef _Float16 f16x8 __attribute__((ext_vector_type(8)));
typedef _Float16 f16x4 __attribute__((ext_vector_type(4)));
typedef float    f32x4 __attribute__((ext_vector_type(4)));

#define MFMA_K32(A, B, C) __builtin_amdgcn_mfma_f32_16x16x32_f16(A, B, C, 0, 0, 0)
#define MFMA_K16(A, B, C) __builtin_amdgcn_mfma_f32_16x16x16f16(A, B, C, 0, 0, 0)

__device__ inline unsigned pack2h(float a, float b) {
    union { _Float16 h[2]; unsigned u; } t;
    t.h[0] = (_Float16)a; t.h[1] = (_Float16)b;
    return t.u;
}

constexpr float CSCALE = 0.18033688011112042f;   // log2(e)/sqrt(64)

// -- prep: Kh = f16(K*CSCALE); Vq packed [B,S/16,64,16]; Mf float bias ------
__global__ __launch_bounds__(256, 4)
void prep_f16(const float* __restrict__ K, const float* __restrict__ V,
              const int* __restrict__ M, _Float16* __restrict__ Kh,
              _Float16* __restrict__ Vq, float* __restrict__ Mf) {
    __shared__ _Float16 sT[64 * 80];          // [d][local_s]
    const int b   = blockIdx.x >> 5;
    const int s0  = (blockIdx.x & 31) * 64;
    const int t   = threadIdx.x;
    const int row = t >> 2;                   // local s 0..63
    const int grp = (t & 3) * 16;             // d group
    const size_t base = ((size_t)b * 2048 + s0 + row) * 64 + grp;
    {   // K: scale + convert, row-major
        union { _Float16 h[16]; f16x8 v[2]; } o;
        const float* p = K + base;
#pragma unroll
        for (int i = 0; i < 16; i += 4) {
            float4 x = *(const float4*)(p + i);
            o.h[i]   = (_Float16)(x.x * CSCALE); o.h[i+1] = (_Float16)(x.y * CSCALE);
            o.h[i+2] = (_Float16)(x.z * CSCALE); o.h[i+3] = (_Float16)(x.w * CSCALE);
        }
        *(f16x8*)(Kh + base) = o.v[0];
        *(f16x8*)(Kh + base + 8) = o.v[1];
    }
    {   // V: convert into LDS transposed sT[d][local_s]
        const float* p = V + base;
#pragma unroll
        for (int i = 0; i < 16; i += 4) {
            float4 x = *(const float4*)(p + i);
            sT[(grp + i    ) * 80 + row] = (_Float16)x.x;
            sT[(grp + i + 1) * 80 + row] = (_Float16)x.y;
            sT[(grp + i + 2) * 80 + row] = (_Float16)x.z;
            sT[(grp + i + 3) * 80 + row] = (_Float16)x.w;
        }
    }
    if (t < 64) {   // mask -> float bias (0 attend, -1e5 masked)
        const size_t s = (size_t)b * 2048 + s0 + t;
        Mf[s] = M[s] ? 0.f : -1.0e5f;
    }
    __syncthreads();
    {   // Vq[b][s>>4][d][s&15]
        const int d = t & 63, g = t >> 6;
        const size_t o = (((size_t)b * 128 + (s0 >> 4) + g) * 64 + d) * 16;
        *(f16x8*)(Vq + o)     = *(const f16x8*)&sT[d * 80 + g * 16];
        *(f16x8*)(Vq + o + 8) = *(const f16x8*)&sT[d * 80 + g * 16 + 8];
    }
}

// -------- v9: v6 + XCD-affinity swizzle ------------------------------------
constexpr int SOSTR = 68;   // padded fp32 row stride for sO

__global__ __launch_bounds__(512, 2)
void attn_f16_v9(const float* __restrict__ Q, const _Float16* __restrict__ Kh,
                 const _Float16* __restrict__ Vq, const float* __restrict__ Mf,
                 float* __restrict__ O) {
    constexpr int S = 2048, D = 64;

    __shared__ float sO[8][32 * SOSTR];   // 69.6 KB partial O
    __shared__ float sL[8][32];           // partial denominators

    const int tid  = threadIdx.x;
    const int w    = tid >> 6;
    const int lane = tid & 63;
    const int l15  = lane & 15;
    const int quad = lane >> 4;

    const int idx = (int)blockIdx.x;      // flat 0..255
    const int stb = idx >> 3;             // 0..31
    const int bb  = idx & 7;              // batch == XCD affinity (id % 8)

    for (int phase = 0; phase < 2; ++phase) {
        const int batch = bb ^ phase;
        const int st    = phase ? 63 - stb : stb;
        const int n_kt  = st + 1;                  // 32-key tiles (causal)
        const int qg0   = st * 32;
        const size_t bq = (size_t)batch * S;
        const _Float16* Kb = Kh + bq * D;
        const _Float16* Vb = Vq + bq * D;
        const float*    Mb = Mf + bq;

        // Q fragments for the two 16-row frags: rows qg0 + f*16 + l15
        f16x8 qf[2][2];
#pragma unroll
        for (int f = 0; f < 2; ++f) {
            const float* qp = Q + (bq + qg0 + f * 16 + l15) * D + quad * 8;
#pragma unroll
            for (int dc = 0; dc < 2; ++dc) {
                float4 x0 = *(const float4*)(qp + dc * 32);
                float4 x1 = *(const float4*)(qp + dc * 32 + 4);
                union { unsigned u[4]; f16x8 v; } t;
                t.u[0] = pack2h(x0.x, x0.y); t.u[1] = pack2h(x0.z, x0.w);
                t.u[2] = pack2h(x1.x, x1.y); t.u[3] = pack2h(x1.z, x1.w);
                qf[f][dc] = t.v;
            }
        }

        f32x4 acc[2][4];
        float lacc[2] = {0.f, 0.f};
#pragma unroll
        for (int f = 0; f < 2; ++f)
#pragma unroll
            for (int c = 0; c < 4; ++c) { acc[f][c][0] = acc[f][c][1] = acc[f][c][2] = acc[f][c][3] = 0.f; }

        // ---- prime K prefetch for tile t = w -----------------------------
        f16x8 kn[2][2];
        if (w < n_kt) {
            const int kb = w * 32;
#pragma unroll
            for (int kg = 0; kg < 2; ++kg)
#pragma unroll
                for (int dc = 0; dc < 2; ++dc)
                    kn[kg][dc] = *(const f16x8*)(Kb + (size_t)(kb + kg * 16 + l15) * D + dc * 32 + quad * 8);
        }

        for (int t = w; t < n_kt; t += 8) {
            const int kb = t * 32;

            // ---- issue V + mask for THIS tile (used ~300cyc later) -------
            f16x4 vf[2][4];
#pragma unroll
            for (int kg = 0; kg < 2; ++kg)
#pragma unroll
                for (int c = 0; c < 4; ++c)
                    vf[kg][c] = *(const f16x4*)(Vb + ((size_t)((kb >> 4) + kg) * 64 + c * 16 + l15) * 16 + quad * 4);
            const float4 mbias0 = *(const float4*)(Mb + kb + quad * 4);
            const float4 mbias1 = *(const float4*)(Mb + kb + 16 + quad * 4);

            // ---- S^T = K Q^T on the prefetched K fragments ---------------
            f32x4 scT[2][2];   // [f][kg]
#pragma unroll
            for (int f = 0; f < 2; ++f) {
                f32x4 z; z[0] = z[1] = z[2] = z[3] = 0.f;
                f32x4 y0 = MFMA_K32(kn[0][0], qf[f][0], z);
                scT[f][0] = MFMA_K32(kn[0][1], qf[f][1], y0);
                f32x4 y1 = MFMA_K32(kn[1][0], qf[f][0], z);
                scT[f][1] = MFMA_K32(kn[1][1], qf[f][1], y1);
            }

            // ---- issue next tile's K loads -------------------------------
            if (t + 8 < n_kt) {
                const int kb2 = kb + 256;
#pragma unroll
                for (int kg = 0; kg < 2; ++kg)
#pragma unroll
                    for (int dc = 0; dc < 2; ++dc)
                        kn[kg][dc] = *(const f16x8*)(Kb + (size_t)(kb2 + kg * 16 + l15) * D + dc * 32 + quad * 8);
            }

            // ---- masked exp + PV for both q-frags ------------------------
            const float mb0[4] = {mbias0.x, mbias0.y, mbias0.z, mbias0.w};
            const float mb1[4] = {mbias1.x, mbias1.y, mbias1.z, mbias1.w};
#pragma unroll
            for (int f = 0; f < 2; ++f) {
                const int qrow = qg0 + f * 16 + l15;
                f16x4 pf0, pf1;
                {
                    union { _Float16 h[4]; f16x4 v; } pp;
#pragma unroll
                    for (int r = 0; r < 4; ++r) {
                        float e = __builtin_amdgcn_exp2f(scT[f][0][r] + mb0[r]);
                        if (kb + 32 > qg0) {            // diagonal tile only
                            const int key = kb + quad * 4 + r;
                            e = (key <= qrow) ? e : 0.f;
                        }
                        lacc[f] += e;
                        pp.h[r] = (_Float16)e;
                    }
                    pf0 = pp.v;
#pragma unroll
                    for (int r = 0; r < 4; ++r) {
                        float e = __builtin_amdgcn_exp2f(scT[f][1][r] + mb1[r]);
                        if (kb + 32 > qg0) {
                            const int key = kb + 16 + quad * 4 + r;
                            e = (key <= qrow) ? e : 0.f;
                        }
                        lacc[f] += e;
                        pp.h[r] = (_Float16)e;
                    }
                    pf1 = pp.v;
                }
                acc[f][0] = MFMA_K16(pf0, vf[0][0], acc[f][0]);
                acc[f][1] = MFMA_K16(pf0, vf[0][1], acc[f][1]);
                acc[f][2] = MFMA_K16(pf0, vf[0][2], acc[f][2]);
                acc[f][3] = MFMA_K16(pf0, vf[0][3], acc[f][3]);
                acc[f][0] = MFMA_K16(pf1, vf[1][0], acc[f][0]);
                acc[f][1] = MFMA_K16(pf1, vf[1][1], acc[f][1]);
                acc[f][2] = MFMA_K16(pf1, vf[1][2], acc[f][2]);
                acc[f][3] = MFMA_K16(pf1, vf[1][3], acc[f][3]);
            }
        }

        // denom partials: sum over quads (lanes sharing l15)
#pragma unroll
        for (int f = 0; f < 2; ++f) {
            lacc[f] += __shfl_xor(lacc[f], 16, 64);
            lacc[f] += __shfl_xor(lacc[f], 32, 64);
        }

        // write partials, block-reduce, store
#pragma unroll
        for (int f = 0; f < 2; ++f)
#pragma unroll
            for (int c = 0; c < 4; ++c)
#pragma unroll
                for (int r = 0; r < 4; ++r)
                    sO[w][(f * 16 + quad * 4 + r) * SOSTR + c * 16 + l15] = acc[f][c][r];
        if (lane < 16) { sL[w][l15] = lacc[0]; sL[w][16 + l15] = lacc[1]; }
        __syncthreads();
        {
            const int row = tid >> 4;          // 0..31
            const int col = (tid & 15) * 4;    // 0,4,..,60
            float a0 = 0.f, a1 = 0.f, a2 = 0.f, a3 = 0.f, l = 0.f;
#pragma unroll
            for (int w2 = 0; w2 < 8; ++w2) {
                const float* p = &sO[w2][row * SOSTR + col];
                a0 += p[0]; a1 += p[1]; a2 += p[2]; a3 += p[3];
                l  += sL[w2][row];
            }
            const float inv = 1.f / fmaxf(l, 1e-37f);
            float4 o; o.x = a0 * inv; o.y = a1 * inv; o.z = a2 * inv; o.w = a3 * inv;
            *(float4*)(&O[(bq + qg0 + row) * D + col]) = o;
        }
        __syncthreads();   // sO/sL reused next phase
    }
}

// ---------------- fallback (fp32 inputs, no ws) ----------------------------
constexpr int PSTR = 40;
__global__ __launch_bounds__(512, 4)
void attn_f16_slow(const float* __restrict__ Q, const float* __restrict__ K,
                   const float* __restrict__ V, const int* __restrict__ M,
                   float* __restrict__ O) {
    constexpr int S = 2048, D = 64;
    __shared__ __align__(16) _Float16 sP[8][16 * PSTR];
    __shared__ float sO[8][16 * 64];
    __shared__ float sL[8][16];
    const int tid = threadIdx.x, w = tid >> 6, lane = tid & 63;
    const int l15 = lane & 15, quad = lane >> 4;
    for (int phase = 0; phase < 2; ++phase) {
        const int batch = (int)blockIdx.y ^ phase;
        const int tile  = phase ? 127 - (int)blockIdx.x : (int)blockIdx.x;
        const int n_kt  = tile / 2 + 1;
        const int qg0   = tile * 16;
        const size_t bq = (size_t)batch * S;
        f16x8 qf[2];
        {
            const float* qp = Q + (bq + qg0 + l15) * D + quad * 8;
#pragma unroll
            for (int dc = 0; dc < 2; ++dc) {
                float4 x0 = *(const float4*)(qp + dc * 32);
                float4 x1 = *(const float4*)(qp + dc * 32 + 4);
                union { unsigned u[4]; f16x8 v; } t;
                t.u[0] = pack2h(x0.x, x0.y); t.u[1] = pack2h(x0.z, x0.w);
                t.u[2] = pack2h(x1.x, x1.y); t.u[3] = pack2h(x1.z, x1.w);
                qf[dc] = t.v;
            }
        }
        f32x4 acc[4]; float lacc[4];
#pragma unroll
        for (int c = 0; c < 4; ++c) { acc[c][0] = acc[c][1] = acc[c][2] = acc[c][3] = 0.f; }
#pragma unroll
        for (int r = 0; r < 4; ++r) lacc[r] = 0.f;
        for (int t = w; t < n_kt; t += 8) {
            const int kb = t * 32;
            f16x8 kf[2][2];
            {
                const float* kp = K + (bq + kb + l15) * D + quad * 8;
#pragma unroll
                for (int kg = 0; kg < 2; ++kg)
#pragma unroll
                    for (int dc = 0; dc < 2; ++dc) {
                        float4 x0 = *(const float4*)(kp + kg * 16 * D + dc * 32);
                        float4 x1 = *(const float4*)(kp + kg * 16 * D + dc * 32 + 4);
                        union { unsigned u[4]; f16x8 v; } tt;
                        tt.u[0] = pack2h(x0.x * CSCALE, x0.y * CSCALE);
                        tt.u[1] = pack2h(x0.z * CSCALE, x0.w * CSCALE);
                        tt.u[2] = pack2h(x1.x * CSCALE, x1.y * CSCALE);
                        tt.u[3] = pack2h(x1.z * CSCALE, x1.w * CSCALE);
                        kf[kg][dc] = tt.v;
                    }
            }
            float vr[4][8];
            {
                const float* vp = V + (bq + kb + quad * 8) * D + l15;
#pragma unroll
                for (int c = 0; c < 4; ++c)
#pragma unroll
                    for (int j = 0; j < 8; ++j)
                        vr[c][j] = vp[j * D + c * 16];
            }
            const int m0 = M[bq + kb + l15];
            const int m1 = M[bq + kb + 16 + l15];
            f32x4 sc[2];
#pragma unroll
            for (int kg = 0; kg < 2; ++kg) {
                f32x4 z; z[0] = z[1] = z[2] = z[3] = 0.f;
                z = MFMA_K32(qf[0], kf[kg][0], z);
                sc[kg] = MFMA_K32(qf[1], kf[kg][1], z);
            }
            float p[2][4];
#pragma unroll
            for (int kg = 0; kg < 2; ++kg) {
                const int key = kb + kg * 16 + l15;
                const int mv  = kg ? m1 : m0;
#pragma unroll
                for (int r = 0; r < 4; ++r) {
                    const int qrow = qg0 + quad * 4 + r;
                    float e  = __builtin_amdgcn_exp2f(sc[kg][r]);
                    bool  ok = (key <= qrow) && (mv != 0);
                    float pv = ok ? e : 0.f;
                    p[kg][r] = pv;
                    lacc[r] += pv;
                }
            }
            _Float16* sPw = sP[w];
#pragma unroll
            for (int kg = 0; kg < 2; ++kg)
#pragma unroll
                for (int r = 0; r < 4; ++r)
                    sPw[(quad * 4 + r) * PSTR + kg * 16 + l15] = (_Float16)p[kg][r];
            f16x8 pf = *(const f16x8*)(&sPw[l15 * PSTR + quad * 8]);
#pragma unroll
            for (int c = 0; c < 4; ++c) {
                union { unsigned u[4]; f16x8 v; } tt;
                tt.u[0] = pack2h(vr[c][0], vr[c][1]);
                tt.u[1] = pack2h(vr[c][2], vr[c][3]);
                tt.u[2] = pack2h(vr[c][4], vr[c][5]);
                tt.u[3] = pack2h(vr[c][6], vr[c][7]);
                acc[c] = MFMA_K32(pf, tt.v, acc[c]);
            }
        }
#pragma unroll
        for (int r = 0; r < 4; ++r) {
            float s = lacc[r];
            s += __shfl_xor(s, 1, 64);
            s += __shfl_xor(s, 2, 64);
            s += __shfl_xor(s, 4, 64);
            s += __shfl_xor(s, 8, 64);
            lacc[r] = s;
        }
#pragma unroll
        for (int c = 0; c < 4; ++c)
#pragma unroll
            for (int r = 0; r < 4; ++r)
                sO[w][(quad * 4 + r) * 64 + c * 16 + l15] = acc[c][r];
        if (l15 == 0) {
#pragma unroll
            for (int r = 0; r < 4; ++r) sL[w][quad * 4 + r] = lacc[r];
        }
        __syncthreads();
        {
            const int row = tid >> 5;
            const int col = (tid & 31) * 2;
            float a = 0.f, b = 0.f, l = 0.f;
#pragma unroll
            for (int w2 = 0; w2 < 8; ++w2) {
                a += sO[w2][row * 64 + col];
                b += sO[w2][row * 64 + col + 1];
                l += sL[w2][row];
            }
            const float inv = 1.f / fmaxf(l, 1e-37f);
            float2 o; o.x = a * inv; o.y = b * inv;
            *(float2*)(&O[(bq + qg0 + row) * D + col]) = o;
        }
        __syncthreads();
    }
}

extern "C" void kernel_launch(void* const* d_in, const int* in_sizes, int n_in,
                              void* d_out, int out_size, void* d_ws, size_t ws_size,
                              hipStream_t stream) {
    const float* Q = (const float*)d_in[0];
    const float* K = (const float*)d_in[1];
    const float* V = (const float*)d_in[2];
    const int*   M = (const int*)d_in[3];
    float*       O = (float*)d_out;
    const size_t n_kv = (size_t)8 * 2048 * 64;
    const size_t need = n_kv * 2 * sizeof(_Float16) + (size_t)8 * 2048 * sizeof(float);
    if (ws_size >= need) {
        _Float16* Kh = (_Float16*)d_ws;
        _Float16* Vq = Kh + n_kv;
        float*    Mf = (float*)(Vq + n_kv);
        hipLaunchKernelGGL(prep_f16, dim3(256), dim3(256), 0, stream, K, V, M, Kh, Vq, Mf);
        hipLaunchKernelGGL(attn_f16_v9, dim3(256), dim3(512), 0, stream, Q, Kh, Vq, Mf, O);
    } else {
        hipLaunchKernelGGL(attn_f16_slow, dim3(64, 8), dim3(512), 0, stream, Q, K, V, M, O);
    }
}